// Round 1
// baseline (1318.655 us; speedup 1.0000x reference)
//
#include <hip/hip_runtime.h>

// PointNetSetAbstraction on MI355X.
// Stages: FPS -> kNN+group -> g-moments -> (L1+L2 fused, y2 bf16) -> stats2 -> (L3 + max/min + stats3) -> finalize.
// Index-selection paths (FPS argmax, kNN argsort) use __fmul_rn/__fadd_rn to match numpy eval order bitwise.

#define Bc 16
#define Nn 4096
#define Ss 1024
#define Kk 32
#define COLS (Bc*Ss*Kk)   /* 524288 */
#define EPSF 1e-5f

typedef unsigned long long ull;
typedef unsigned int uint32;

__device__ __forceinline__ unsigned short f2bf(float f){
  uint32 u = __float_as_uint(f);
  uint32 r = (u + 0x7fffu + ((u>>16)&1u)) >> 16;
  return (unsigned short)r;
}
__device__ __forceinline__ float bf2f(unsigned short h){ return __uint_as_float(((uint32)h)<<16); }

// ---------------- Kernel 1: farthest point sampling (one block per batch) ----------------
__global__ __launch_bounds__(512) void fps_kernel(const float* __restrict__ xyz,
                                                  const int* __restrict__ init_far,
                                                  float* __restrict__ new_xyz){
  __shared__ float sx[Nn*3];          // 48 KB: whole batch point cloud
  __shared__ ull wk[2][8];            // per-wave max keys, parity double-buffered
  int b = blockIdx.x, t = threadIdx.x;
  const float4* xb4 = (const float4*)(xyz + (size_t)b*Nn*3);
  float4* sx4 = (float4*)sx;
  for(int i=t;i<Nn*3/4;i+=512) sx4[i]=xb4[i];
  __syncthreads();
  float px[8],py[8],pz[8],dd[8];
  #pragma unroll
  for(int j=0;j<8;j++){ int n=t+512*j; px[j]=sx[n*3]; py[j]=sx[n*3+1]; pz[j]=sx[n*3+2]; dd[j]=1e10f; }
  int far = init_far[b];
  int lane = t & 63, wid = t >> 6;
  for(int it=0; it<Ss; it++){
    if(t==0){
      new_xyz[((size_t)b*Ss+it)*3+0]=sx[far*3];
      new_xyz[((size_t)b*Ss+it)*3+1]=sx[far*3+1];
      new_xyz[((size_t)b*Ss+it)*3+2]=sx[far*3+2];
    }
    float cx=sx[far*3], cy=sx[far*3+1], cz=sx[far*3+2];
    ull best=0;
    #pragma unroll
    for(int j=0;j<8;j++){
      float dx=px[j]-cx, dy=py[j]-cy, dz=pz[j]-cz;
      float d=__fadd_rn(__fadd_rn(__fmul_rn(dx,dx),__fmul_rn(dy,dy)),__fmul_rn(dz,dz));
      float nd=fminf(dd[j],d); dd[j]=nd;
      // max over (dist, then smallest index): pack dist bits high, (N-1-idx) low
      ull key=((ull)__float_as_uint(nd)<<32)|(uint32)(Nn-1-(t+512*j));
      best = key>best?key:best;
    }
    #pragma unroll
    for(int m=32;m>=1;m>>=1){ ull o=__shfl_xor(best,m,64); best = o>best?o:best; }
    if(lane==0) wk[it&1][wid]=best;
    __syncthreads();
    ull gbest=wk[it&1][0];
    #pragma unroll
    for(int w=1;w<8;w++){ ull o=wk[it&1][w]; gbest=o>gbest?o:gbest; }
    far = Nn-1-(int)(uint32)(gbest&0xffffffffu);
  }
}

// ---------------- Kernel 2: kNN among new_xyz (stable (d,j) selection), group from RAW xyz ----------------
__global__ __launch_bounds__(256) void knn_kernel(const float* __restrict__ xyz,
                                                  const float* __restrict__ new_xyz,
                                                  float* __restrict__ gout){
  __shared__ float nx[Ss*3];          // 12 KB: sampled points of this batch
  int b = blockIdx.x >> 8;            // 256 blocks per batch (4 queries each)
  int t = threadIdx.x;
  const float4* src=(const float4*)(new_xyz + (size_t)b*Ss*3);
  float4* dst=(float4*)nx;
  for(int i=t;i<Ss*3/4;i+=256) dst[i]=src[i];
  __syncthreads();
  int wid=t>>6, lane=t&63;
  int s=(blockIdx.x&255)*4+wid;
  float qx=nx[s*3],qy=nx[s*3+1],qz=nx[s*3+2];
  ull key[16];
  #pragma unroll
  for(int i=0;i<16;i++){
    int j=lane+64*i;
    float dx=nx[j*3]-qx, dy=nx[j*3+1]-qy, dz=nx[j*3+2]-qz;
    float d=__fadd_rn(__fadd_rn(__fmul_rn(dx,dx),__fmul_rn(dy,dy)),__fmul_rn(dz,dz));
    key[i]=((ull)(__float_as_uint(d)+1u)<<32)|(uint32)j;  // +1 so key>0 always (last starts at 0)
  }
  ull last=0; int myn=0;
  for(int r=0;r<33;r++){             // extract 33 smallest; r=0 is self (d=0)
    ull cur=~0ull;
    #pragma unroll
    for(int i=0;i<16;i++){ ull k2=key[i]; if(k2>last && k2<cur) cur=k2; }
    #pragma unroll
    for(int m=32;m>=1;m>>=1){ ull o=__shfl_xor(cur,m,64); cur = o<cur?o:cur; }
    last=cur;
    if(r>=1 && lane==r-1) myn=(int)(uint32)(cur&0xffffffffu);
  }
  if(lane<Kk){
    int j=myn;                        // index into sampled set, gathered from RAW xyz (reference quirk)
    const float* p=xyz + (size_t)b*Nn*3 + (size_t)j*3;
    float* go = gout + ((size_t)(b*Ss+s)*Kk + lane)*3;
    go[0]=p[0]-qx; go[1]=p[1]-qy; go[2]=p[2]-qz;
  }
}

// ---------------- Kernel 3: grouped-coord moments (exact layer-1 BN stats) ----------------
__global__ __launch_bounds__(256) void gmom_kernel(const float* __restrict__ g, float* __restrict__ stats){
  __shared__ float sm[9];
  int t=threadIdx.x;
  if(t<9) sm[t]=0.f;
  __syncthreads();
  float a[9]={0,0,0,0,0,0,0,0,0};
  for(int col=blockIdx.x*256+t; col<COLS; col+=gridDim.x*256){
    float x=g[(size_t)col*3],y=g[(size_t)col*3+1],z=g[(size_t)col*3+2];
    a[0]+=x;a[1]+=y;a[2]+=z;a[3]+=x*x;a[4]+=y*y;a[5]+=z*z;a[6]+=x*y;a[7]+=x*z;a[8]+=y*z;
  }
  #pragma unroll
  for(int i=0;i<9;i++){
    float v=a[i];
    #pragma unroll
    for(int m=32;m>=1;m>>=1) v+=__shfl_xor(v,m,64);
    if((t&63)==0) atomicAdd(&sm[i],v);
  }
  __syncthreads();
  if(t<9) atomicAdd(&stats[t],sm[t]);
}

// ---------------- Kernel 4: layer1(BN,relu) + layer2 GEMM, y2 stored bf16 ----------------
__global__ __launch_bounds__(256) void layer12_kernel(const float* __restrict__ g,
    const float* __restrict__ W1,const float* __restrict__ b1,const float* __restrict__ g1,const float* __restrict__ be1,
    const float* __restrict__ W2,const float* __restrict__ b2,
    const float* __restrict__ stats, unsigned short* __restrict__ y2){
  __shared__ float x2s[64*128];       // [c][col] 32 KB, stride-1 cols -> conflict-free
  __shared__ float w2s[64*65];        // padded rows
  __shared__ float w1s[192], b1s[64], sc1[64], sh1[64], b2s[64];
  int t=threadIdx.x;
  for(int i=t;i<4096;i+=256){ w2s[(i>>6)*65+(i&63)]=W2[i]; }
  if(t<192) w1s[t]=W1[t];
  if(t<64){ b1s[t]=b1[t]; b2s[t]=b2[t]; }
  __syncthreads();
  if(t<64){
    const float n1=1.0f/COLS;
    float ex=stats[0]*n1,ey=stats[1]*n1,ez=stats[2]*n1;
    float cxx=stats[3]*n1-ex*ex, cyy=stats[4]*n1-ey*ey, czz=stats[5]*n1-ez*ez;
    float cxy=stats[6]*n1-ex*ey, cxz=stats[7]*n1-ex*ez, cyz=stats[8]*n1-ey*ez;
    float wx=w1s[t*3],wy=w1s[t*3+1],wz=w1s[t*3+2];
    float m=wx*ex+wy*ey+wz*ez+b1s[t];
    float v=wx*wx*cxx+wy*wy*cyy+wz*wz*czz+2.f*(wx*wy*cxy+wx*wz*cxz+wy*wz*cyz);
    float sc=g1[t]*rsqrtf(v+EPSF);
    sc1[t]=sc; sh1[t]=be1[t]-m*sc;
  }
  __syncthreads();
  { // Phase A: layer1 + BN1 + relu -> x2s
    int col=t&127, c0=(t>>7)*32;
    size_t cg=(size_t)blockIdx.x*128+col;
    float gx=g[cg*3],gy=g[cg*3+1],gz=g[cg*3+2];
    for(int c=c0;c<c0+32;c++){
      float y=fmaf(w1s[c*3],gx,fmaf(w1s[c*3+1],gy,fmaf(w1s[c*3+2],gz,b1s[c])));
      x2s[c*128+col]=fmaxf(fmaf(y,sc1[c],sh1[c]),0.f);
    }
  }
  __syncthreads();
  // Phase B: 64x128 tile, To=4 x Tc=8 per thread
  int og=t>>4, cgi=t&15;
  float acc[4][8];
  #pragma unroll
  for(int r=0;r<4;r++){ float bb=b2s[og*4+r];
    #pragma unroll
    for(int j=0;j<8;j++) acc[r][j]=bb; }
  for(int c=0;c<64;c++){
    float xv[8];
    #pragma unroll
    for(int j=0;j<8;j++) xv[j]=x2s[c*128+cgi+16*j];
    #pragma unroll
    for(int r=0;r<4;r++){
      float w=w2s[(og*4+r)*65+c];
      #pragma unroll
      for(int j=0;j<8;j++) acc[r][j]=fmaf(w,xv[j],acc[r][j]);
    }
  }
  #pragma unroll
  for(int j=0;j<8;j++){
    size_t col=(size_t)blockIdx.x*128+cgi+16*j;
    ushort4 pk;
    pk.x=f2bf(acc[0][j]); pk.y=f2bf(acc[1][j]); pk.z=f2bf(acc[2][j]); pk.w=f2bf(acc[3][j]);
    *(ushort4*)(y2 + col*64 + og*4)=pk;
  }
}

// ---------------- Kernel 5: per-channel sum/sumsq of y2 (layer-2 BN stats) ----------------
__global__ __launch_bounds__(256) void stats2_kernel(const unsigned short* __restrict__ y2, float* __restrict__ stats){
  __shared__ float red[128];
  int t=threadIdx.x;
  if(t<128) red[t]=0.f;
  __syncthreads();
  int c4=t&15;
  float s[4]={0,0,0,0}, q[4]={0,0,0,0};
  int col=(blockIdx.x*256+t)>>4;
  int stride=(gridDim.x*256)>>4;
  for(; col<COLS; col+=stride){
    ushort4 u=*(const ushort4*)(y2+(size_t)col*64+c4*4);
    float f0=bf2f(u.x),f1=bf2f(u.y),f2=bf2f(u.z),f3=bf2f(u.w);
    s[0]+=f0;s[1]+=f1;s[2]+=f2;s[3]+=f3;
    q[0]=fmaf(f0,f0,q[0]);q[1]=fmaf(f1,f1,q[1]);q[2]=fmaf(f2,f2,q[2]);q[3]=fmaf(f3,f3,q[3]);
  }
  #pragma unroll
  for(int e=0;e<4;e++){ atomicAdd(&red[c4*4+e],s[e]); atomicAdd(&red[64+c4*4+e],q[e]); }
  __syncthreads();
  if(t<64) atomicAdd(&stats[16+t],red[t]);
  else if(t<128) atomicAdd(&stats[80+(t-64)],red[t]);
}

// ---------------- Kernel 6: BN2+relu, layer3 GEMM, k-max/min, layer-3 BN stats ----------------
__global__ __launch_bounds__(256) void layer3_kernel(const unsigned short* __restrict__ y2,
    const float* __restrict__ g2,const float* __restrict__ be2,
    const float* __restrict__ W3,const float* __restrict__ b3,
    float* __restrict__ stats, float* __restrict__ ymax, float* __restrict__ ymin){
  __shared__ float x3s[64*64];            // [c][col] 16 KB
  __shared__ unsigned short w3s[128*66];  // bf16, padded rows (33 uints/row)
  __shared__ float y3s[128*65];           // [o][col] padded
  __shared__ float sc2[64], sh2[64], b3s[128];
  int t=threadIdx.x;
  if(t<64){
    const float n1=1.0f/COLS;
    float m=stats[16+t]*n1;
    float v=stats[80+t]*n1-m*m;
    float sc=g2[t]*rsqrtf(v+EPSF);
    sc2[t]=sc; sh2[t]=be2[t]-m*sc;
  }
  if(t<128) b3s[t]=b3[t];
  for(int i=t;i<8192;i+=256){ w3s[(i>>6)*66+(i&63)]=f2bf(W3[i]); }
  __syncthreads();
  int og=t>>4, cgi=t&15;   // Phase B roles
  int q=t>>7, oo=t&127;    // Phase C roles
  float asum=0.f, asq=0.f;
  const uint32* w3u=(const uint32*)w3s;
  for(int tl=0; tl<4; tl++){
    int colbase=(blockIdx.x*4+tl)*64;
    { // Phase A: BN2 + relu of y2 tile -> x3s
      int col=t&63, c0=(t>>6)*16;
      const unsigned short* yp=y2+(size_t)(colbase+col)*64+c0;
      #pragma unroll
      for(int h=0;h<2;h++){
        uint4 u=((const uint4*)yp)[h];
        uint32 ua[4]={u.x,u.y,u.z,u.w};
        #pragma unroll
        for(int e=0;e<4;e++){
          int c=c0+h*8+e*2;
          float flo=__uint_as_float(ua[e]<<16);
          float fhi=__uint_as_float(ua[e]&0xffff0000u);
          x3s[c*64+col]=fmaxf(fmaf(flo,sc2[c],sh2[c]),0.f);
          x3s[(c+1)*64+col]=fmaxf(fmaf(fhi,sc2[c+1],sh2[c+1]),0.f);
        }
      }
    }
    __syncthreads();
    // Phase B: 128x64 tile, To=8 x Tc=4
    float acc[8][4];
    #pragma unroll
    for(int r=0;r<8;r++){ float bb=b3s[og*8+r];
      #pragma unroll
      for(int j=0;j<4;j++) acc[r][j]=bb; }
    for(int c2=0;c2<32;c2++){
      float x0[4],x1[4];
      #pragma unroll
      for(int j=0;j<4;j++){ x0[j]=x3s[(2*c2)*64+cgi+16*j]; x1[j]=x3s[(2*c2+1)*64+cgi+16*j]; }
      #pragma unroll
      for(int r=0;r<8;r++){
        uint32 w=w3u[(og*8+r)*33+c2];
        float w0=__uint_as_float(w<<16);
        float w1=__uint_as_float(w&0xffff0000u);
        #pragma unroll
        for(int j=0;j<4;j++) acc[r][j]=fmaf(w1,x1[j],fmaf(w0,x0[j],acc[r][j]));
      }
    }
    #pragma unroll
    for(int r=0;r<8;r++){
      #pragma unroll
      for(int j=0;j<4;j++) y3s[(og*8+r)*65+cgi+16*j]=acc[r][j];
    }
    __syncthreads();
    { // Phase C: per-(query,channel) reduce over k=32
      float mx=-3.4e38f, mn=3.4e38f, su=0.f, sq=0.f;
      #pragma unroll
      for(int k=0;k<32;k++){
        float yv=y3s[oo*65+q*32+k];
        mx=fmaxf(mx,yv); mn=fminf(mn,yv); su+=yv; sq=fmaf(yv,yv,sq);
      }
      asum+=su; asq+=sq;
      int qg=(colbase>>5)+q;
      int bb=qg>>10, ss=qg&1023;
      ymax[((size_t)bb*128+oo)*1024+ss]=mx;
      ymin[((size_t)bb*128+oo)*1024+ss]=mn;
    }
    __syncthreads();
  }
  // combine q=0/1 partials, one atomic per channel per block
  if(t>=128){ x3s[t-128]=asum; x3s[128+(t-128)]=asq; }
  __syncthreads();
  if(t<128){
    asum+=x3s[t]; asq+=x3s[128+t];
    atomicAdd(&stats[144+t],asum);
    atomicAdd(&stats[272+t],asq);
  }
}

// ---------------- Kernel 7: finalize BN3 + relu + (max via sign of scale) ----------------
__global__ __launch_bounds__(256) void finalize_kernel(const float* __restrict__ ymax,const float* __restrict__ ymin,
    const float* __restrict__ g3,const float* __restrict__ be3,const float* __restrict__ stats,
    float* __restrict__ outp){
  int idx=blockIdx.x*256+threadIdx.x;
  int o=(idx>>10)&127;
  const float n1=1.0f/COLS;
  float m=stats[144+o]*n1;
  float v=stats[272+o]*n1-m*m;
  float sc=g3[o]*rsqrtf(v+EPSF);
  float sh=be3[o]-m*sc;
  float val=(sc>=0.f)?ymax[idx]:ymin[idx];
  outp[idx]=fmaxf(fmaf(val,sc,sh),0.f);
}

extern "C" void kernel_launch(void* const* d_in, const int* in_sizes, int n_in,
                              void* d_out, int out_size, void* d_ws, size_t ws_size,
                              hipStream_t stream){
  const float* xyz=(const float*)d_in[0];
  const int* initf=(const int*)d_in[1];
  const float* W1=(const float*)d_in[2]; const float* b1=(const float*)d_in[3];
  const float* g1=(const float*)d_in[4]; const float* be1=(const float*)d_in[5];
  const float* W2=(const float*)d_in[6]; const float* b2=(const float*)d_in[7];
  const float* g2=(const float*)d_in[8]; const float* be2=(const float*)d_in[9];
  const float* W3=(const float*)d_in[10]; const float* b3=(const float*)d_in[11];
  const float* g3=(const float*)d_in[12]; const float* be3=(const float*)d_in[13];
  float* out=(float*)d_out;
  char* ws=(char*)d_ws;
  // ws layout (bytes): [65536 spare][g: 6291456][stats: 4096][y2 bf16: 67108864][ymax: 8388608][ymin: 8388608]
  float* gbuf=(float*)(ws+65536);
  float* stats=(float*)(ws+6356992);
  unsigned short* y2=(unsigned short*)(ws+6361088);
  float* ymax=(float*)(ws+73469952);
  float* ymin=(float*)(ws+81858560);
  hipMemsetAsync(stats,0,4096,stream);
  fps_kernel<<<16,512,0,stream>>>(xyz,initf,out);
  knn_kernel<<<4096,256,0,stream>>>(xyz,out,gbuf);
  gmom_kernel<<<1024,256,0,stream>>>(gbuf,stats);
  layer12_kernel<<<4096,256,0,stream>>>(gbuf,W1,b1,g1,be1,W2,b2,stats,y2);
  stats2_kernel<<<2048,256,0,stream>>>(y2,stats);
  layer3_kernel<<<2048,256,0,stream>>>(y2,g2,be2,W3,b3,stats,ymax,ymin);
  finalize_kernel<<<8192,256,0,stream>>>(ymax,ymin,g3,be3,stats,out+49152);
}